// Round 1
// 97.327 us; speedup vs baseline: 1.0405x; 1.0405x over previous
//
#include <hip/hip_runtime.h>
#include <math.h>

// Problem constants: B=8, N=128, D=128, C=32, H=256
#define BB 8
#define NN 128
#define DD 128
#define CC 32
#define HH 256
#define PP 16256            // N*(N-1)
#define ROWS (BB*NN)        // 1024
#define NBUCK 64            // loss accumulation buckets (x2: bce, match)
#define TI 32               // i-tile (2 i's per thread: ti and ti+16)
#define TJ 16               // j-tile
#define LPAD 260            // LDS row stride in floats (256 + 4 -> 16B pad)

// ws layout (floats):
//   Lp      : ROWS*HH   x@W1[0:128] + ctx@W1[256:288] + b1 folded in
//   Rp      : ROWS*HH   x@W1[128:256]
//   buckets : 128       [0..64) weighted-bce partials, [64..128) match partials
//   counter : 1 int     (at buckets[128], zeroed along with buckets)

// ---------------------------------------------------------------------------
// Kernel 1: per-row projections. 256 blocks x 256 threads, 4 rows/block.
// (was 128 blocks x 8 rows: only half the CUs had waves; now every SIMD on
//  every CU gets one wave. W1 L2 traffic doubles to ~75MB but that's ~2.2us
//  at L2 BW and overlaps the FMA stream.)
// thread h owns output column h for its 4 rows. Also zeroes buckets+counter.
// ---------------------------------------------------------------------------
__global__ __launch_bounds__(256) void k1_stage(
    const float* __restrict__ x, const float* __restrict__ ctx,
    const float* __restrict__ W1, const float* __restrict__ b1,
    float* __restrict__ Lp, float* __restrict__ Rp,
    float* __restrict__ buckets)
{
    __shared__ float xs[4 * DD];
    __shared__ float cs[CC];
    const int t  = threadIdx.x;
    const int r0 = blockIdx.x * 4;      // 4 rows share batch b (N=128 mult of 4)
    const int b  = r0 >> 7;

    // block 0 zeroes buckets (128 floats) + ticket counter (1 int at [128])
    if (blockIdx.x == 0 && t < 2 * NBUCK + 1) buckets[t] = 0.f;

    // cooperative load: 4 rows x 128 floats = 512 floats = 128 float4
    if (t < 128) ((float4*)xs)[t] = ((const float4*)(x + r0 * DD))[t];
    else if (t < 128 + CC) cs[t - 128] = ctx[b * CC + (t - 128)];
    __syncthreads();

    const int h = t;
    float accL[4] = {0.f, 0.f, 0.f, 0.f};
    float accR[4] = {0.f, 0.f, 0.f, 0.f};

#pragma unroll 8
    for (int k = 0; k < DD; ++k) {
        const float wl = W1[k * HH + h];            // coalesced across h
        const float wr = W1[(k + DD) * HH + h];
#pragma unroll
        for (int r = 0; r < 4; ++r) {
            const float xv = xs[r * DD + k];        // LDS broadcast / b128 vec
            accL[r] = fmaf(xv, wl, accL[r]);
            accR[r] = fmaf(xv, wr, accR[r]);
        }
    }

    float cb = b1[h];
#pragma unroll 4
    for (int c = 0; c < CC; ++c) cb = fmaf(cs[c], W1[(2 * DD + c) * HH + h], cb);

#pragma unroll
    for (int r = 0; r < 4; ++r) {
        Lp[(r0 + r) * HH + h] = accL[r] + cb;
        Rp[(r0 + r) * HH + h] = accR[r];
    }
}

// ---------------------------------------------------------------------------
// Kernel 2: pair kernel, GEMM-style tiling with 2-way register blocking.
// 256 blocks x 256 threads; block = (b, 32 i's, 16 j's); thread = 2 pairs
// (i0+ti, j) and (i0+ti+16, j) sharing the Rs read -> 3 ds_read_b128 per
// 2 pairs (was 2 per pair). Last block computes the final loss.
// ---------------------------------------------------------------------------
__global__ __launch_bounds__(256) void k2_pairs(
    const float* __restrict__ Lp, const float* __restrict__ Rp,
    const float* __restrict__ W2, const float* __restrict__ b2,
    const int* __restrict__ labels, const int* __restrict__ origin,
    float* __restrict__ pred, float* __restrict__ buckets,
    int* __restrict__ counter, float* __restrict__ loss)
{
    __shared__ float Ls[TI][LPAD];
    __shared__ float Rs[TJ][LPAD];
    __shared__ float sred[8];
    __shared__ int amLast;

    const int tid = threadIdx.x;
    const int blk = blockIdx.x;
    const int b   = blk >> 5;                 // 32 tiles per batch (4 iT x 8 jT)
    const int i0  = ((blk >> 3) & 3) * TI;
    const int j0  = (blk & 7) * TJ;

    // stage tiles: Ls 32x256 floats = 2048 float4 (8/thread), Rs 16x256 = 1024 (4/thread)
#pragma unroll
    for (int q = 0; q < 8; ++q) {
        const int idx = q * 256 + tid;        // [0,2048)
        const int r   = idx >> 6;             // 64 float4 per row
        const int c4  = (idx & 63) * 4;
        *(float4*)(&Ls[r][c4]) = *(const float4*)(Lp + (b * NN + i0 + r) * HH + c4);
    }
#pragma unroll
    for (int q = 0; q < 4; ++q) {
        const int idx = q * 256 + tid;        // [0,1024)
        const int r   = idx >> 6;
        const int c4  = (idx & 63) * 4;
        *(float4*)(&Rs[r][c4]) = *(const float4*)(Rp + (b * NN + j0 + r) * HH + c4);
    }
    __syncthreads();

    const int ti = tid >> 4, tj = tid & 15;
    float4 acc0 = make_float4(0.f, 0.f, 0.f, 0.f);
    float4 acc1 = make_float4(0.f, 0.f, 0.f, 0.f);
#pragma unroll 8
    for (int hc = 0; hc < HH / 4; ++hc) {
        const float4 l0 = *(const float4*)(&Ls[ti][hc * 4]);      // 4 rows/wave, conflict-free
        const float4 l1 = *(const float4*)(&Ls[ti + 16][hc * 4]);
        const float4 r  = *(const float4*)(&Rs[tj][hc * 4]);      // 2-way alias (free)
        const float4 w  = ((const float4*)W2)[hc];                // wave-uniform -> s_load
        acc0.x = fmaf(fmaxf(l0.x + r.x, 0.f), w.x, acc0.x);
        acc0.y = fmaf(fmaxf(l0.y + r.y, 0.f), w.y, acc0.y);
        acc0.z = fmaf(fmaxf(l0.z + r.z, 0.f), w.z, acc0.z);
        acc0.w = fmaf(fmaxf(l0.w + r.w, 0.f), w.w, acc0.w);
        acc1.x = fmaf(fmaxf(l1.x + r.x, 0.f), w.x, acc1.x);
        acc1.y = fmaf(fmaxf(l1.y + r.y, 0.f), w.y, acc1.y);
        acc1.z = fmaf(fmaxf(l1.z + r.z, 0.f), w.z, acc1.z);
        acc1.w = fmaf(fmaxf(l1.w + r.w, 0.f), w.w, acc1.w);
    }

    const int i  = i0 + ti;
    const int i2 = i + 16;
    const int j  = j0 + tj;
    const float b2v = b2[0];
    const float z0 = acc0.x + acc0.y + acc0.z + acc0.w + b2v;
    const float z1 = acc1.x + acc1.y + acc1.z + acc1.w + b2v;

    float bcew = 0.f, mt = 0.f;
    const int lj = labels[b * NN + j];
    const int oj = origin[b * NN + j];
    const int wj = (oj == 3 || oj == 4 || oj == 5) ? 1 : ((oj == 1) ? -1 : 0);
    if (i != j) {
        pred[b * PP + i * 127 + j - (j > i ? 1 : 0)] = z0;
        const int li = labels[b * NN + i];
        const float match = (li == lj && li >= 0) ? 1.f : 0.f;
        const int oi = origin[b * NN + i];
        const int wi = (oi == 3 || oi == 4 || oi == 5) ? 1 : ((oi == 1) ? -1 : 0);
        const float weight = (float)(1 + (wi & wj));   // {0,1,2}
        bcew += (fmaxf(z0, 0.f) - z0 * match + log1pf(expf(-fabsf(z0)))) * weight;
        mt += match;
    }
    if (i2 != j) {
        pred[b * PP + i2 * 127 + j - (j > i2 ? 1 : 0)] = z1;
        const int li = labels[b * NN + i2];
        const float match = (li == lj && li >= 0) ? 1.f : 0.f;
        const int oi = origin[b * NN + i2];
        const int wi = (oi == 3 || oi == 4 || oi == 5) ? 1 : ((oi == 1) ? -1 : 0);
        const float weight = (float)(1 + (wi & wj));
        bcew += (fmaxf(z1, 0.f) - z1 * match + log1pf(expf(-fabsf(z1)))) * weight;
        mt += match;
    }

    // block-level loss reduce: one wave butterfly per thread-block
#pragma unroll
    for (int m = 1; m < 64; m <<= 1) {
        bcew += __shfl_xor(bcew, m, 64);
        mt   += __shfl_xor(mt, m, 64);
    }
    const int w64 = tid >> 6, lane = tid & 63;
    if (lane == 0) { sred[w64] = bcew; sred[4 + w64] = mt; }
    __syncthreads();
    if (tid == 0) {
        const float s1 = sred[0] + sred[1] + sred[2] + sred[3];
        const float s2 = sred[4] + sred[5] + sred[6] + sred[7];
        const int bkt = blk & (NBUCK - 1);
        atomicAdd(buckets + bkt, s1);
        atomicAdd(buckets + NBUCK + bkt, s2);
        __threadfence();
        const int old = atomicAdd(counter, 1);
        amLast = (old == (int)gridDim.x - 1) ? 1 : 0;
    }
    __syncthreads();

    // last block computes loss = sum(bce*w)/sum(match).
    // Read buckets via atomicAdd(p,0) -> device-coherent (plain loads could hit
    // a stale per-XCD L2 line; L2s are not cross-coherent).
    if (amLast && tid < 64) {
        float v1 = atomicAdd(buckets + tid, 0.f);
        float v2 = atomicAdd(buckets + NBUCK + tid, 0.f);
#pragma unroll
        for (int m = 1; m < 64; m <<= 1) {
            v1 += __shfl_xor(v1, m, 64);
            v2 += __shfl_xor(v2, m, 64);
        }
        if (tid == 0) loss[0] = v1 / v2;
    }
}

extern "C" void kernel_launch(void* const* d_in, const int* in_sizes, int n_in,
                              void* d_out, int out_size, void* d_ws, size_t ws_size,
                              hipStream_t stream)
{
    const float* x      = (const float*)d_in[0];
    const float* ctx    = (const float*)d_in[1];
    const float* W1     = (const float*)d_in[2];
    const float* b1     = (const float*)d_in[3];
    const float* W2     = (const float*)d_in[4];
    const float* b2     = (const float*)d_in[5];
    const int*   labels = (const int*)d_in[6];
    const int*   origin = (const int*)d_in[7];

    float* pred = (float*)d_out;        // B*P floats
    float* loss = pred + BB * PP;       // 1 float

    float* Lp      = (float*)d_ws;
    float* Rp      = Lp + ROWS * HH;
    float* buckets = Rp + ROWS * HH;    // 128 floats + 1 int counter
    int*   counter = (int*)(buckets + 2 * NBUCK);

    k1_stage<<<ROWS / 4, 256, 0, stream>>>(x, ctx, W1, b1, Lp, Rp, buckets);
    k2_pairs<<<256, 256, 0, stream>>>(Lp, Rp, W2, b2, labels, origin,
                                      pred, buckets, counter, loss);
}